// Round 13
// baseline (22.597 us; speedup 1.0000x reference)
//
#include <hip/hip_runtime.h>
#include <math.h>

// Problem constants: Q=4, N=64, H=256, C=1, L=1024
#define QQ 4
#define NN 64
#define HH 256

// SINGLE kernel, 1024 blocks x 256 threads.
// Block b -> qh via XCD-aware swizzle (qh = (b%8)*128 + b/8) so the 16
// blocks sharing each 64B output line co-reside on one XCD (L2 merge).
// Phase A: pole data held per-lane in REGISTERS (lane = pole index);
//   the 64-pole loop broadcasts via v_readlane -> SGPR (VALU pipe),
//   leaving the per-CU LDS pipe to the FFT only. Deferred-imag resolvent
//   sums + rank-1 correction; tan via HW v_sin/v_cos (rev = l/2048).
// Phase B: 512-pt complex inverse Stockham FFT in LDS; final stage
//   scatter-stores directly to out[s][q][h].

__device__ __forceinline__ float vcos(float rev) { return __builtin_amdgcn_cosf(rev); }
__device__ __forceinline__ float vsin(float rev) { return __builtin_amdgcn_sinf(rev); }
__device__ __forceinline__ float rdlane(float v, int n) {
    return __int_as_float(__builtin_amdgcn_readlane(__float_as_int(v), n));
}

__global__ __launch_bounds__(256)
void tssm_kernel(const float* __restrict__ diagonal,      // [Q][N]
                 const float* __restrict__ lowrank,       // [Q][N]
                 const float* __restrict__ timestep,      // [Q][H]
                 const float* __restrict__ input_matrix,  // [Q][N]
                 const float* __restrict__ output_matrix, // [Q][1][H][N]
                 float* __restrict__ out)                 // [L][Q][1][H]
{
    __shared__ __align__(16) float2 bufA[512];
    __shared__ __align__(16) float2 bufB[513];

    const int b    = blockIdx.x;                  // 0..1023
    const int qh   = ((b & 7) << 7) + (b >> 3);   // XCD-aware swizzle
    const int q    = qh >> 8;
    const int t    = threadIdx.x;
    const int lane = t & 63;

    const float tv   = __expf(timestep[qh]);
    const float invt = __builtin_amdgcn_rcpf(tv);

    // ---- per-lane pole data (lane = pole index); same in every wave ----
    const float pa  = __expf(diagonal[q * NN + lane]);
    const float pB  = input_matrix[q * NN + lane];
    const float pP  = lowrank[q * NN + lane];
    const float pC  = output_matrix[qh * NN + lane];
    const float va  = pa;
    const float va2 = pa * pa;
    const float vw0 = pB * pC;
    const float vw1 = pB * pP;
    const float vw2 = pP * pC;
    const float vw3 = pP * pP;

    // X[512] = (t/2) * sum_n B*C  (exact real limit) — wave reduction
    if (t < 64) {
        float acc = vw0;
        #pragma unroll
        for (int off = 32; off >= 1; off >>= 1) acc += __shfl_xor(acc, off, 64);
        if (t == 0) bufB[512] = make_float2(0.5f * tv * acc, 0.0f);
    }

    // ---------------- Phase A: bins l = t and l = t+256 ----------------
    // tan(pi*l/1024) = sin(2*pi*l/2048)/cos(2*pi*l/2048), HW trig (revolutions)
    const float rv0 = (float)t         * (1.0f / 2048.0f);
    const float rv1 = (float)(t + 256) * (1.0f / 2048.0f);
    const float tn0 = vsin(rv0) * __builtin_amdgcn_rcpf(vcos(rv0));
    const float tn1 = vsin(rv1) * __builtin_amdgcn_rcpf(vcos(rv1));
    const float ze0 = 2.0f * tn0 * invt, ze1 = 2.0f * tn1 * invt;
    const float z20 = ze0 * ze0,         z21 = ze1 * ze1;

    // Re k_j = sum w_j*a*g ; S_j = sum w_j*g ; Im k_j = -ze*S_j
    float r0_0=0,r0_1=0,r0_2=0,r0_3=0, s0_0=0,s0_1=0,s0_2=0,s0_3=0;
    float r1_0=0,r1_1=0,r1_2=0,r1_3=0, s1_0=0,s1_1=0,s1_2=0,s1_3=0;

    #pragma unroll
    for (int n = 0; n < NN; ++n) {
        const float sa  = rdlane(va,  n);   // SGPR broadcasts (VALU pipe)
        const float sa2 = rdlane(va2, n);
        const float sw0 = rdlane(vw0, n);
        const float sw1 = rdlane(vw1, n);
        const float sw2 = rdlane(vw2, n);
        const float sw3 = rdlane(vw3, n);
        {
            float g  = __builtin_amdgcn_rcpf(sa2 + z20);
            float ag = sa * g;
            r0_0 = fmaf(sw0, ag, r0_0); s0_0 = fmaf(sw0, g, s0_0);
            r0_1 = fmaf(sw1, ag, r0_1); s0_1 = fmaf(sw1, g, s0_1);
            r0_2 = fmaf(sw2, ag, r0_2); s0_2 = fmaf(sw2, g, s0_2);
            r0_3 = fmaf(sw3, ag, r0_3); s0_3 = fmaf(sw3, g, s0_3);
        }
        {
            float g  = __builtin_amdgcn_rcpf(sa2 + z21);
            float ag = sa * g;
            r1_0 = fmaf(sw0, ag, r1_0); s1_0 = fmaf(sw0, g, s1_0);
            r1_1 = fmaf(sw1, ag, r1_1); s1_1 = fmaf(sw1, g, s1_1);
            r1_2 = fmaf(sw2, ag, r1_2); s1_2 = fmaf(sw2, g, s1_2);
            r1_3 = fmaf(sw3, ag, r1_3); s1_3 = fmaf(sw3, g, s1_3);
        }
    }

    {   // bin l = t
        float i0 = -ze0 * s0_0, i1 = -ze0 * s0_1, i2 = -ze0 * s0_2, i3 = -ze0 * s0_3;
        float dr = 1.0f + r0_3, di = i3;
        float nr = r0_2 * r0_1 - i2 * i1;
        float ni = r0_2 * i1 + i2 * r0_1;
        float invm = __builtin_amdgcn_rcpf(fmaf(dr, dr, di * di));
        float qr = (nr * dr + ni * di) * invm;
        float qi = (ni * dr - nr * di) * invm;
        float Kr = r0_0 - qr, Ki = i0 - qi;
        bufB[t] = make_float2(fmaf(-tn0, Ki, Kr), fmaf(tn0, Kr, Ki));
    }
    {   // bin l = t + 256
        float i0 = -ze1 * s1_0, i1 = -ze1 * s1_1, i2 = -ze1 * s1_2, i3 = -ze1 * s1_3;
        float dr = 1.0f + r1_3, di = i3;
        float nr = r1_2 * r1_1 - i2 * i1;
        float ni = r1_2 * i1 + i2 * r1_1;
        float invm = __builtin_amdgcn_rcpf(fmaf(dr, dr, di * di));
        float qr = (nr * dr + ni * di) * invm;
        float qi = (ni * dr - nr * di) * invm;
        float Kr = r1_0 - qr, Ki = i0 - qi;
        bufB[t + 256] = make_float2(fmaf(-tn1, Ki, Kr), fmaf(tn1, Kr, Ki));
    }
    __syncthreads();

    // ---------------- Y build ----------------
    const float c1 = vcos((float)t * 0.0009765625f);   // cos(2*pi*t/1024)
    const float s1 = vsin((float)t * 0.0009765625f);

    float Y0r, Y0i, Y1r, Y1i;
    {   // k = t
        float2 A = bufB[t], Bv = bufB[512 - t];
        float Dr = A.x - Bv.x, Di = A.y + Bv.y;
        float twDr = fmaf(c1, Dr, -s1 * Di);
        float twDi = fmaf(c1, Di,  s1 * Dr);
        Y0r = 0.5f * (A.x + Bv.x) - 0.5f * twDi;
        Y0i = 0.5f * (A.y - Bv.y) + 0.5f * twDr;
    }
    {   // k = t+256
        float2 A = bufB[t + 256], Bv = bufB[256 - t];
        float Dr = A.x - Bv.x, Di = A.y + Bv.y;
        float twDr = fmaf(-s1, Dr, -c1 * Di);
        float twDi = fmaf(-s1, Di,  c1 * Dr);
        Y1r = 0.5f * (A.x + Bv.x) - 0.5f * twDi;
        Y1i = 0.5f * (A.y - Bv.y) + 0.5f * twDr;
    }

    // ---------------- Stage Ns=1 (registers) ----------------
    ((float4*)bufA)[t] = make_float4(Y0r + Y1r, Y0i + Y1i, Y0r - Y1r, Y0i - Y1i);
    __syncthreads();

    // ---------------- Stages Ns = 2..128 ----------------
    #define FFT_STAGE(NS, REVNS, SRC, DST)                                   \
    {                                                                        \
        float2 u = (SRC)[t];                                                 \
        float2 v = (SRC)[t + 256];                                           \
        int   base = t & ((NS) - 1);                                         \
        float rev = (float)base * (REVNS);                                   \
        float cw = vcos(rev), sw = vsin(rev);                                \
        float vr = fmaf(cw, v.x, -sw * v.y);                                 \
        float vi = fmaf(cw, v.y,  sw * v.x);                                 \
        int dj = ((t & ~((NS) - 1)) << 1) | base;                            \
        (DST)[dj]        = make_float2(u.x + vr, u.y + vi);                  \
        (DST)[dj + (NS)] = make_float2(u.x - vr, u.y - vi);                  \
        __syncthreads();                                                     \
    }

    FFT_STAGE(2,   0.25f,         bufA, bufB)
    FFT_STAGE(4,   0.125f,        bufB, bufA)
    FFT_STAGE(8,   0.0625f,       bufA, bufB)
    FFT_STAGE(16,  0.03125f,      bufB, bufA)
    FFT_STAGE(32,  0.015625f,     bufA, bufB)
    FFT_STAGE(64,  0.0078125f,    bufB, bufA)
    FFT_STAGE(128, 0.00390625f,   bufA, bufB)
    #undef FFT_STAGE

    // -------- Stage Ns=256 -> direct scattered store to out[s][q][h] --------
    {
        float2 u = bufB[t];
        float2 v = bufB[t + 256];
        float rev = (float)t * 0.001953125f;   // t/512 revolutions
        float cw = vcos(rev), sw = vsin(rev);
        float vr = fmaf(cw, v.x, -sw * v.y);
        float vi = fmaf(cw, v.y,  sw * v.x);
        const float sc = 1.0f / 512.0f;
        const int s0 = 2 * t;
        out[( s0        << 10) + qh] = (u.x + vr) * sc;
        out[((s0 + 1)   << 10) + qh] = (u.y + vi) * sc;
        out[((s0 + 512) << 10) + qh] = (u.x - vr) * sc;
        out[((s0 + 513) << 10) + qh] = (u.y - vi) * sc;
    }
}

extern "C" void kernel_launch(void* const* d_in, const int* in_sizes, int n_in,
                              void* d_out, int out_size, void* d_ws, size_t ws_size,
                              hipStream_t stream) {
    (void)in_sizes; (void)n_in; (void)out_size; (void)d_ws; (void)ws_size;
    const float* diagonal      = (const float*)d_in[0];
    const float* lowrank       = (const float*)d_in[1];
    const float* timestep      = (const float*)d_in[2];
    const float* input_matrix  = (const float*)d_in[3];
    const float* output_matrix = (const float*)d_in[4];
    float* out = (float*)d_out;

    hipLaunchKernelGGL(tssm_kernel, dim3(QQ * HH), dim3(256), 0, stream,
                       diagonal, lowrank, timestep, input_matrix, output_matrix, out);
}

// Round 14
// 18.613 us; speedup vs baseline: 1.2140x; 1.2140x over previous
//
#include <hip/hip_runtime.h>
#include <math.h>

// Problem constants: Q=4, N=64, H=256, C=1, L=1024
#define QQ 4
#define NN 64
#define HH 256

// SINGLE kernel, 1024 blocks x 256 threads (R12 structure).
// Block b -> qh via XCD-aware swizzle (qh = (b%8)*128 + b/8): the 16 blocks
// sharing each 64B output line co-reside on one XCD (writeback-L2 merge).
// Phase A: LDS pole table (broadcast reads are cheap — R13 ablation), the
//   two bins per thread computed in PACKED 2xf32 (v_pk_fma_f32 et al.) via
//   float2 ext_vector accumulators: 12 instr/pole vs 22 scalar.
//   tan via HW v_sin/v_cos (rev = l/2048) — R13-validated accuracy.
// Phase B: 512-pt complex inverse Stockham FFT in LDS (R5-proven),
//   final stage scatter-stores directly to out[s][q][h].

typedef float f2 __attribute__((ext_vector_type(2)));

__device__ __forceinline__ float vcos(float rev) { return __builtin_amdgcn_cosf(rev); }
__device__ __forceinline__ float vsin(float rev) { return __builtin_amdgcn_sinf(rev); }

__global__ __launch_bounds__(256)
void tssm_kernel(const float* __restrict__ diagonal,      // [Q][N]
                 const float* __restrict__ lowrank,       // [Q][N]
                 const float* __restrict__ timestep,      // [Q][H]
                 const float* __restrict__ input_matrix,  // [Q][N]
                 const float* __restrict__ output_matrix, // [Q][1][H][N]
                 float* __restrict__ out)                 // [L][Q][1][H]
{
    __shared__ __align__(16) float2 bufA[512];
    __shared__ __align__(16) float2 bufB[513];
    __shared__ __align__(16) float4 sP4[NN];   // (a, a^2, w0=B*C, w1=B*P)
    __shared__ __align__(8)  float2 sP2[NN];   // (w2=P*C, w3=P*P)

    const int b  = blockIdx.x;                  // 0..1023
    const int qh = ((b & 7) << 7) + (b >> 3);   // XCD-aware swizzle
    const int q  = qh >> 8;
    const int t  = threadIdx.x;

    const float tv   = __expf(timestep[qh]);
    const float invt = __builtin_amdgcn_rcpf(tv);

    // ---- pole table setup (wave 0) + X[512] ----
    if (t < NN) {
        float a  = __expf(diagonal[q * NN + t]);
        float B  = input_matrix[q * NN + t];
        float P  = lowrank[q * NN + t];
        float Cm = output_matrix[qh * NN + t];
        float w0 = B * Cm;
        sP4[t] = make_float4(a, a * a, w0, B * P);
        sP2[t] = make_float2(P * Cm, P * P);
        float acc = w0;
        #pragma unroll
        for (int off = 32; off >= 1; off >>= 1) acc += __shfl_xor(acc, off, 64);
        if (t == 0) bufB[512] = make_float2(0.5f * tv * acc, 0.0f);
    }
    __syncthreads();

    // ---------------- Phase A: bins l = t and l = t+256 (packed 2xf32) ----
    const float rv0 = (float)t         * (1.0f / 2048.0f);
    const float rv1 = (float)(t + 256) * (1.0f / 2048.0f);
    const float tn0 = vsin(rv0) * __builtin_amdgcn_rcpf(vcos(rv0));
    const float tn1 = vsin(rv1) * __builtin_amdgcn_rcpf(vcos(rv1));
    const float ze0 = 2.0f * tn0 * invt, ze1 = 2.0f * tn1 * invt;

    const f2 z2v = { ze0 * ze0, ze1 * ze1 };

    f2 r_0 = 0.0f, r_1 = 0.0f, r_2 = 0.0f, r_3 = 0.0f;   // Re sums (w*a*g)
    f2 s_0 = 0.0f, s_1 = 0.0f, s_2 = 0.0f, s_3 = 0.0f;   // S  sums (w*g)

    #pragma unroll 8
    for (int n = 0; n < NN; ++n) {
        float4 p4 = sP4[n];
        float2 p2 = sP2[n];
        f2 d;
        d = p4.y + z2v;                         // v_pk_add
        f2 g;
        g.x = __builtin_amdgcn_rcpf(d.x);       // trans pipe
        g.y = __builtin_amdgcn_rcpf(d.y);
        f2 ag = p4.x * g;                       // v_pk_mul
        f2 w0v = p4.z, w1v = p4.w, w2v = p2.x, w3v = p2.y;
        r_0 = __builtin_elementwise_fma(w0v, ag, r_0);   // v_pk_fma x8
        s_0 = __builtin_elementwise_fma(w0v, g,  s_0);
        r_1 = __builtin_elementwise_fma(w1v, ag, r_1);
        s_1 = __builtin_elementwise_fma(w1v, g,  s_1);
        r_2 = __builtin_elementwise_fma(w2v, ag, r_2);
        s_2 = __builtin_elementwise_fma(w2v, g,  s_2);
        r_3 = __builtin_elementwise_fma(w3v, ag, r_3);
        s_3 = __builtin_elementwise_fma(w3v, g,  s_3);
    }

    {   // bin l = t  (.x components)
        float i0 = -ze0 * s_0.x, i1 = -ze0 * s_1.x, i2 = -ze0 * s_2.x, i3 = -ze0 * s_3.x;
        float dr = 1.0f + r_3.x, di = i3;
        float nr = r_2.x * r_1.x - i2 * i1;
        float ni = r_2.x * i1 + i2 * r_1.x;
        float invm = __builtin_amdgcn_rcpf(fmaf(dr, dr, di * di));
        float qr = (nr * dr + ni * di) * invm;
        float qi = (ni * dr - nr * di) * invm;
        float Kr = r_0.x - qr, Ki = i0 - qi;
        bufB[t] = make_float2(fmaf(-tn0, Ki, Kr), fmaf(tn0, Kr, Ki));
    }
    {   // bin l = t + 256  (.y components)
        float i0 = -ze1 * s_0.y, i1 = -ze1 * s_1.y, i2 = -ze1 * s_2.y, i3 = -ze1 * s_3.y;
        float dr = 1.0f + r_3.y, di = i3;
        float nr = r_2.y * r_1.y - i2 * i1;
        float ni = r_2.y * i1 + i2 * r_1.y;
        float invm = __builtin_amdgcn_rcpf(fmaf(dr, dr, di * di));
        float qr = (nr * dr + ni * di) * invm;
        float qi = (ni * dr - nr * di) * invm;
        float Kr = r_0.y - qr, Ki = i0 - qi;
        bufB[t + 256] = make_float2(fmaf(-tn1, Ki, Kr), fmaf(tn1, Kr, Ki));
    }
    __syncthreads();

    // ---------------- Y build ----------------
    const float c1 = vcos((float)t * 0.0009765625f);   // cos(2*pi*t/1024)
    const float s1 = vsin((float)t * 0.0009765625f);

    float Y0r, Y0i, Y1r, Y1i;
    {   // k = t
        float2 A = bufB[t], Bv = bufB[512 - t];
        float Dr = A.x - Bv.x, Di = A.y + Bv.y;
        float twDr = fmaf(c1, Dr, -s1 * Di);
        float twDi = fmaf(c1, Di,  s1 * Dr);
        Y0r = 0.5f * (A.x + Bv.x) - 0.5f * twDi;
        Y0i = 0.5f * (A.y - Bv.y) + 0.5f * twDr;
    }
    {   // k = t+256
        float2 A = bufB[t + 256], Bv = bufB[256 - t];
        float Dr = A.x - Bv.x, Di = A.y + Bv.y;
        float twDr = fmaf(-s1, Dr, -c1 * Di);
        float twDi = fmaf(-s1, Di,  c1 * Dr);
        Y1r = 0.5f * (A.x + Bv.x) - 0.5f * twDi;
        Y1i = 0.5f * (A.y - Bv.y) + 0.5f * twDr;
    }

    // ---------------- Stage Ns=1 (registers) ----------------
    ((float4*)bufA)[t] = make_float4(Y0r + Y1r, Y0i + Y1i, Y0r - Y1r, Y0i - Y1i);
    __syncthreads();

    // ---------------- Stages Ns = 2..128 ----------------
    #define FFT_STAGE(NS, REVNS, SRC, DST)                                   \
    {                                                                        \
        float2 u = (SRC)[t];                                                 \
        float2 v = (SRC)[t + 256];                                           \
        int   base = t & ((NS) - 1);                                         \
        float rev = (float)base * (REVNS);                                   \
        float cw = vcos(rev), sw = vsin(rev);                                \
        float vr = fmaf(cw, v.x, -sw * v.y);                                 \
        float vi = fmaf(cw, v.y,  sw * v.x);                                 \
        int dj = ((t & ~((NS) - 1)) << 1) | base;                            \
        (DST)[dj]        = make_float2(u.x + vr, u.y + vi);                  \
        (DST)[dj + (NS)] = make_float2(u.x - vr, u.y - vi);                  \
        __syncthreads();                                                     \
    }

    FFT_STAGE(2,   0.25f,         bufA, bufB)
    FFT_STAGE(4,   0.125f,        bufB, bufA)
    FFT_STAGE(8,   0.0625f,       bufA, bufB)
    FFT_STAGE(16,  0.03125f,      bufB, bufA)
    FFT_STAGE(32,  0.015625f,     bufA, bufB)
    FFT_STAGE(64,  0.0078125f,    bufB, bufA)
    FFT_STAGE(128, 0.00390625f,   bufA, bufB)
    #undef FFT_STAGE

    // -------- Stage Ns=256 -> direct scattered store to out[s][q][h] --------
    {
        float2 u = bufB[t];
        float2 v = bufB[t + 256];
        float rev = (float)t * 0.001953125f;   // t/512 revolutions
        float cw = vcos(rev), sw = vsin(rev);
        float vr = fmaf(cw, v.x, -sw * v.y);
        float vi = fmaf(cw, v.y,  sw * v.x);
        const float sc = 1.0f / 512.0f;
        const int s0 = 2 * t;
        out[( s0        << 10) + qh] = (u.x + vr) * sc;
        out[((s0 + 1)   << 10) + qh] = (u.y + vi) * sc;
        out[((s0 + 512) << 10) + qh] = (u.x - vr) * sc;
        out[((s0 + 513) << 10) + qh] = (u.y - vi) * sc;
    }
}

extern "C" void kernel_launch(void* const* d_in, const int* in_sizes, int n_in,
                              void* d_out, int out_size, void* d_ws, size_t ws_size,
                              hipStream_t stream) {
    (void)in_sizes; (void)n_in; (void)out_size; (void)d_ws; (void)ws_size;
    const float* diagonal      = (const float*)d_in[0];
    const float* lowrank       = (const float*)d_in[1];
    const float* timestep      = (const float*)d_in[2];
    const float* input_matrix  = (const float*)d_in[3];
    const float* output_matrix = (const float*)d_in[4];
    float* out = (float*)d_out;

    hipLaunchKernelGGL(tssm_kernel, dim3(QQ * HH), dim3(256), 0, stream,
                       diagonal, lowrank, timestep, input_matrix, output_matrix, out);
}

// Round 15
// 18.116 us; speedup vs baseline: 1.2474x; 1.0275x over previous
//
#include <hip/hip_runtime.h>
#include <math.h>

// Problem constants: Q=4, N=64, H=256, C=1, L=1024
#define QQ 4
#define NN 64
#define HH 256

// SINGLE kernel, 1024 blocks x 256 threads (R14 structure).
// Block b -> qh via XCD-aware swizzle (qh = (b%8)*128 + b/8): the 16 blocks
// sharing each 64B output line co-reside on one XCD (writeback-L2 merge).
// Phase A: LDS pole table packed as 2 poles / 3 x float4 (96 ds_read_b128
//   per thread vs 128 mixed reads), two bins per thread in PACKED 2xf32
//   (v_pk_fma_f32) via float2 ext_vector accumulators.
//   tan via HW v_sin/v_cos (rev = l/2048) — R13/R14-validated accuracy.
// Phase B: 512-pt complex inverse Stockham FFT in LDS (R5-proven),
//   final stage scatter-stores directly to out[s][q][h].

typedef float f2 __attribute__((ext_vector_type(2)));

__device__ __forceinline__ float vcos(float rev) { return __builtin_amdgcn_cosf(rev); }
__device__ __forceinline__ float vsin(float rev) { return __builtin_amdgcn_sinf(rev); }

__global__ __launch_bounds__(256)
void tssm_kernel(const float* __restrict__ diagonal,      // [Q][N]
                 const float* __restrict__ lowrank,       // [Q][N]
                 const float* __restrict__ timestep,      // [Q][H]
                 const float* __restrict__ input_matrix,  // [Q][N]
                 const float* __restrict__ output_matrix, // [Q][1][H][N]
                 float* __restrict__ out)                 // [L][Q][1][H]
{
    __shared__ __align__(16) float2 bufA[512];
    __shared__ __align__(16) float2 bufB[513];
    __shared__ __align__(16) float  sPf[NN * 6];   // 2 poles per 12 floats (3 x float4)

    const int b  = blockIdx.x;                  // 0..1023
    const int qh = ((b & 7) << 7) + (b >> 3);   // XCD-aware swizzle
    const int q  = qh >> 8;
    const int t  = threadIdx.x;

    const float tv   = __expf(timestep[qh]);
    const float invt = __builtin_amdgcn_rcpf(tv);

    // ---- pole table setup (wave 0) + X[512] ----
    // pole n -> floats [ (n>>1)*12 + (n&1)*6 .. +5 ] = (a, a^2, w0, w1, w2, w3)
    if (t < NN) {
        float a  = __expf(diagonal[q * NN + t]);
        float B  = input_matrix[q * NN + t];
        float P  = lowrank[q * NN + t];
        float Cm = output_matrix[qh * NN + t];
        float w0 = B * Cm;
        const int base = (t >> 1) * 12 + (t & 1) * 6;
        sPf[base + 0] = a;
        sPf[base + 1] = a * a;
        sPf[base + 2] = w0;
        sPf[base + 3] = B * P;
        sPf[base + 4] = P * Cm;
        sPf[base + 5] = P * P;
        float acc = w0;
        #pragma unroll
        for (int off = 32; off >= 1; off >>= 1) acc += __shfl_xor(acc, off, 64);
        if (t == 0) bufB[512] = make_float2(0.5f * tv * acc, 0.0f);
    }
    __syncthreads();

    // ---------------- Phase A: bins l = t and l = t+256 (packed 2xf32) ----
    const float rv0 = (float)t         * (1.0f / 2048.0f);
    const float rv1 = (float)(t + 256) * (1.0f / 2048.0f);
    const float tn0 = vsin(rv0) * __builtin_amdgcn_rcpf(vcos(rv0));
    const float tn1 = vsin(rv1) * __builtin_amdgcn_rcpf(vcos(rv1));
    const float ze0 = 2.0f * tn0 * invt, ze1 = 2.0f * tn1 * invt;

    const f2 z2v = { ze0 * ze0, ze1 * ze1 };

    f2 r_0 = 0.0f, r_1 = 0.0f, r_2 = 0.0f, r_3 = 0.0f;   // Re sums (w*a*g)
    f2 s_0 = 0.0f, s_1 = 0.0f, s_2 = 0.0f, s_3 = 0.0f;   // S  sums (w*g)

    #define POLE(PA, PA2, PW0, PW1, PW2, PW3)                                \
    {                                                                        \
        f2 d = (PA2) + z2v;                       /* v_pk_add */             \
        f2 g;                                                                \
        g.x = __builtin_amdgcn_rcpf(d.x);                                    \
        g.y = __builtin_amdgcn_rcpf(d.y);                                    \
        f2 ag = (PA) * g;                         /* v_pk_mul */             \
        r_0 = __builtin_elementwise_fma((f2)(PW0), ag, r_0);                 \
        s_0 = __builtin_elementwise_fma((f2)(PW0), g,  s_0);                 \
        r_1 = __builtin_elementwise_fma((f2)(PW1), ag, r_1);                 \
        s_1 = __builtin_elementwise_fma((f2)(PW1), g,  s_1);                 \
        r_2 = __builtin_elementwise_fma((f2)(PW2), ag, r_2);                 \
        s_2 = __builtin_elementwise_fma((f2)(PW2), g,  s_2);                 \
        r_3 = __builtin_elementwise_fma((f2)(PW3), ag, r_3);                 \
        s_3 = __builtin_elementwise_fma((f2)(PW3), g,  s_3);                 \
    }

    {
        const float4* __restrict__ T4 = (const float4*)sPf;
        #pragma unroll 4
        for (int p = 0; p < 32; ++p) {
            float4 Av = T4[3 * p];
            float4 Bv = T4[3 * p + 1];
            float4 Cv = T4[3 * p + 2];
            POLE(Av.x, Av.y, Av.z, Av.w, Bv.x, Bv.y)   // pole 2p
            POLE(Bv.z, Bv.w, Cv.x, Cv.y, Cv.z, Cv.w)   // pole 2p+1
        }
    }
    #undef POLE

    {   // bin l = t  (.x components)
        float i0 = -ze0 * s_0.x, i1 = -ze0 * s_1.x, i2 = -ze0 * s_2.x, i3 = -ze0 * s_3.x;
        float dr = 1.0f + r_3.x, di = i3;
        float nr = r_2.x * r_1.x - i2 * i1;
        float ni = r_2.x * i1 + i2 * r_1.x;
        float invm = __builtin_amdgcn_rcpf(fmaf(dr, dr, di * di));
        float qr = (nr * dr + ni * di) * invm;
        float qi = (ni * dr - nr * di) * invm;
        float Kr = r_0.x - qr, Ki = i0 - qi;
        bufB[t] = make_float2(fmaf(-tn0, Ki, Kr), fmaf(tn0, Kr, Ki));
    }
    {   // bin l = t + 256  (.y components)
        float i0 = -ze1 * s_0.y, i1 = -ze1 * s_1.y, i2 = -ze1 * s_2.y, i3 = -ze1 * s_3.y;
        float dr = 1.0f + r_3.y, di = i3;
        float nr = r_2.y * r_1.y - i2 * i1;
        float ni = r_2.y * i1 + i2 * r_1.y;
        float invm = __builtin_amdgcn_rcpf(fmaf(dr, dr, di * di));
        float qr = (nr * dr + ni * di) * invm;
        float qi = (ni * dr - nr * di) * invm;
        float Kr = r_0.y - qr, Ki = i0 - qi;
        bufB[t + 256] = make_float2(fmaf(-tn1, Ki, Kr), fmaf(tn1, Kr, Ki));
    }
    __syncthreads();

    // ---------------- Y build ----------------
    const float c1 = vcos((float)t * 0.0009765625f);   // cos(2*pi*t/1024)
    const float s1 = vsin((float)t * 0.0009765625f);

    float Y0r, Y0i, Y1r, Y1i;
    {   // k = t
        float2 A = bufB[t], Bv = bufB[512 - t];
        float Dr = A.x - Bv.x, Di = A.y + Bv.y;
        float twDr = fmaf(c1, Dr, -s1 * Di);
        float twDi = fmaf(c1, Di,  s1 * Dr);
        Y0r = 0.5f * (A.x + Bv.x) - 0.5f * twDi;
        Y0i = 0.5f * (A.y - Bv.y) + 0.5f * twDr;
    }
    {   // k = t+256
        float2 A = bufB[t + 256], Bv = bufB[256 - t];
        float Dr = A.x - Bv.x, Di = A.y + Bv.y;
        float twDr = fmaf(-s1, Dr, -c1 * Di);
        float twDi = fmaf(-s1, Di,  c1 * Dr);
        Y1r = 0.5f * (A.x + Bv.x) - 0.5f * twDi;
        Y1i = 0.5f * (A.y - Bv.y) + 0.5f * twDr;
    }

    // ---------------- Stage Ns=1 (registers) ----------------
    ((float4*)bufA)[t] = make_float4(Y0r + Y1r, Y0i + Y1i, Y0r - Y1r, Y0i - Y1i);
    __syncthreads();

    // ---------------- Stages Ns = 2..128 ----------------
    #define FFT_STAGE(NS, REVNS, SRC, DST)                                   \
    {                                                                        \
        float2 u = (SRC)[t];                                                 \
        float2 v = (SRC)[t + 256];                                           \
        int   base = t & ((NS) - 1);                                         \
        float rev = (float)base * (REVNS);                                   \
        float cw = vcos(rev), sw = vsin(rev);                                \
        float vr = fmaf(cw, v.x, -sw * v.y);                                 \
        float vi = fmaf(cw, v.y,  sw * v.x);                                 \
        int dj = ((t & ~((NS) - 1)) << 1) | base;                            \
        (DST)[dj]        = make_float2(u.x + vr, u.y + vi);                  \
        (DST)[dj + (NS)] = make_float2(u.x - vr, u.y - vi);                  \
        __syncthreads();                                                     \
    }

    FFT_STAGE(2,   0.25f,         bufA, bufB)
    FFT_STAGE(4,   0.125f,        bufB, bufA)
    FFT_STAGE(8,   0.0625f,       bufA, bufB)
    FFT_STAGE(16,  0.03125f,      bufB, bufA)
    FFT_STAGE(32,  0.015625f,     bufA, bufB)
    FFT_STAGE(64,  0.0078125f,    bufB, bufA)
    FFT_STAGE(128, 0.00390625f,   bufA, bufB)
    #undef FFT_STAGE

    // -------- Stage Ns=256 -> direct scattered store to out[s][q][h] --------
    {
        float2 u = bufB[t];
        float2 v = bufB[t + 256];
        float rev = (float)t * 0.001953125f;   // t/512 revolutions
        float cw = vcos(rev), sw = vsin(rev);
        float vr = fmaf(cw, v.x, -sw * v.y);
        float vi = fmaf(cw, v.y,  sw * v.x);
        const float sc = 1.0f / 512.0f;
        const int s0 = 2 * t;
        out[( s0        << 10) + qh] = (u.x + vr) * sc;
        out[((s0 + 1)   << 10) + qh] = (u.y + vi) * sc;
        out[((s0 + 512) << 10) + qh] = (u.x - vr) * sc;
        out[((s0 + 513) << 10) + qh] = (u.y - vi) * sc;
    }
}

extern "C" void kernel_launch(void* const* d_in, const int* in_sizes, int n_in,
                              void* d_out, int out_size, void* d_ws, size_t ws_size,
                              hipStream_t stream) {
    (void)in_sizes; (void)n_in; (void)out_size; (void)d_ws; (void)ws_size;
    const float* diagonal      = (const float*)d_in[0];
    const float* lowrank       = (const float*)d_in[1];
    const float* timestep      = (const float*)d_in[2];
    const float* input_matrix  = (const float*)d_in[3];
    const float* output_matrix = (const float*)d_in[4];
    float* out = (float*)d_out;

    hipLaunchKernelGGL(tssm_kernel, dim3(QQ * HH), dim3(256), 0, stream,
                       diagonal, lowrank, timestep, input_matrix, output_matrix, out);
}